// Round 1
// baseline (1255.490 us; speedup 1.0000x reference)
//
#include <hip/hip_runtime.h>

#define B_N 16
#define LP_N 1024
#define LQ_N 1024
#define H_N 1024

#define BM 128
#define BN 128
#define BK 8
#define TM 8
#define TN 8
// threads = (BM/TM)*(BN/TN) = 256

template<bool TRANSB, bool BIAS, bool RELU>
__launch_bounds__(256)
__global__ void gemm_k(const float* __restrict__ A, const float* __restrict__ Bmat,
                       const float* __restrict__ bias, float* __restrict__ C,
                       int M, int N, int K,
                       long long sA, long long sB, long long sC)
{
    __shared__ float As[BK][BM];
    __shared__ float Bs[BK][BN];

    const int tid = threadIdx.x;
    const int tx = tid & 15;
    const int ty = tid >> 4;
    const int bn = blockIdx.x * BN;
    const int bm = blockIdx.y * BM;
    const long long z = blockIdx.z;

    A    += z * sA;
    Bmat += z * sB;
    C    += z * sC;

    float acc[TM][TN];
#pragma unroll
    for (int i = 0; i < TM; i++)
#pragma unroll
        for (int j = 0; j < TN; j++) acc[i][j] = 0.f;

    const int arow = tid >> 1;        // 0..127
    const int acol = (tid & 1) * 4;   // 0 or 4
    const int bk_n = tid >> 5;        // 0..7   (normal-B loader)
    const int bn_n = (tid & 31) * 4;  // 0..124

    for (int k0 = 0; k0 < K; k0 += BK) {
        // A tile: BM x BK, store transposed As[k][m]
        float4 a4 = *(const float4*)&A[(long long)(bm + arow) * K + k0 + acol];
        As[acol + 0][arow] = a4.x;
        As[acol + 1][arow] = a4.y;
        As[acol + 2][arow] = a4.z;
        As[acol + 3][arow] = a4.w;
        if (TRANSB) {
            // B given as N x K (row-major); tile BN x BK -> Bs[k][n]
            float4 b4 = *(const float4*)&Bmat[(long long)(bn + arow) * K + k0 + acol];
            Bs[acol + 0][arow] = b4.x;
            Bs[acol + 1][arow] = b4.y;
            Bs[acol + 2][arow] = b4.z;
            Bs[acol + 3][arow] = b4.w;
        } else {
            // B given as K x N (row-major); tile BK x BN -> Bs[k][n]
            float4 b4 = *(const float4*)&Bmat[(long long)(k0 + bk_n) * N + bn + bn_n];
            *(float4*)&Bs[bk_n][bn_n] = b4;
        }
        __syncthreads();
#pragma unroll
        for (int k = 0; k < BK; k++) {
            float a[TM], b[TN];
            *(float4*)&a[0] = *(const float4*)&As[k][ty * TM];
            *(float4*)&a[4] = *(const float4*)&As[k][ty * TM + 4];
            *(float4*)&b[0] = *(const float4*)&Bs[k][tx * TN];
            *(float4*)&b[4] = *(const float4*)&Bs[k][tx * TN + 4];
#pragma unroll
            for (int i = 0; i < TM; i++)
#pragma unroll
                for (int j = 0; j < TN; j++)
                    acc[i][j] = fmaf(a[i], b[j], acc[i][j]);
        }
        __syncthreads();
    }

#pragma unroll
    for (int i = 0; i < TM; i++) {
        const int row = bm + ty * TM + i;
#pragma unroll
        for (int j = 0; j < TN; j += 4) {
            const int col = bn + tx * TN + j;
            float4 v;
            v.x = acc[i][j + 0]; v.y = acc[i][j + 1];
            v.z = acc[i][j + 2]; v.w = acc[i][j + 3];
            if (BIAS) {
                v.x += bias[col + 0]; v.y += bias[col + 1];
                v.z += bias[col + 2]; v.w += bias[col + 3];
            }
            if (RELU) {
                v.x = fmaxf(v.x, 0.f); v.y = fmaxf(v.y, 0.f);
                v.z = fmaxf(v.z, 0.f); v.w = fmaxf(v.w, 0.f);
            }
            *(float4*)&C[(long long)row * N + col] = v;
        }
    }
}

// One block (256 threads) per row of 1024 floats: softmax in place.
__global__ void softmax_k(float* __restrict__ S)
{
    const long long row = blockIdx.x;
    float* r = S + row * (long long)LQ_N;
    const int t = threadIdx.x;
    float4 v = ((float4*)r)[t];

    float m = fmaxf(fmaxf(v.x, v.y), fmaxf(v.z, v.w));
#pragma unroll
    for (int off = 32; off > 0; off >>= 1)
        m = fmaxf(m, __shfl_xor(m, off));

    __shared__ float red[4];
    const int lane = t & 63, wid = t >> 6;
    if (lane == 0) red[wid] = m;
    __syncthreads();
    m = fmaxf(fmaxf(red[0], red[1]), fmaxf(red[2], red[3]));
    __syncthreads();

    v.x = __expf(v.x - m); v.y = __expf(v.y - m);
    v.z = __expf(v.z - m); v.w = __expf(v.w - m);
    float s = v.x + v.y + v.z + v.w;
#pragma unroll
    for (int off = 32; off > 0; off >>= 1)
        s += __shfl_xor(s, off);
    if (lane == 0) red[wid] = s;
    __syncthreads();
    s = red[0] + red[1] + red[2] + red[3];

    const float inv = 1.0f / s;
    v.x *= inv; v.y *= inv; v.z *= inv; v.w *= inv;
    ((float4*)r)[t] = v;
}

extern "C" void kernel_launch(void* const* d_in, const int* in_sizes, int n_in,
                              void* d_out, int out_size, void* d_ws, size_t ws_size,
                              hipStream_t stream)
{
    const float* p    = (const float*)d_in[0];
    const float* q    = (const float*)d_in[1];
    const float* W    = (const float*)d_in[2];
    const float* bias = (const float*)d_in[3];
    float* out = (float*)d_out;

    float* keys   = (float*)d_ws;                                  // B*LQ*H f32 = 64 MB
    float* scores = keys + (long long)B_N * LQ_N * H_N;            // B*LP*LQ f32 = 64 MB

    // keys = q2d @ W + bias   (batch folds into M: W shared across batch)
    gemm_k<false, true, false><<<dim3(H_N / BN, (B_N * LQ_N) / BM, 1), 256, 0, stream>>>(
        q, W, bias, keys, B_N * LQ_N, H_N, H_N, 0, 0, 0);

    // scores[b] = p[b] @ keys[b]^T
    gemm_k<true, false, false><<<dim3(LQ_N / BN, LP_N / BM, B_N), 256, 0, stream>>>(
        p, keys, nullptr, scores, LP_N, LQ_N, H_N,
        (long long)LP_N * H_N, (long long)LQ_N * H_N, (long long)LP_N * LQ_N);

    // softmax along LQ, in place
    softmax_k<<<B_N * LP_N, 256, 0, stream>>>(scores);

    // out[b] = relu(attn[b] @ q[b])
    gemm_k<false, false, true><<<dim3(H_N / BN, LP_N / BM, B_N), 256, 0, stream>>>(
        scores, q, nullptr, out, LP_N, H_N, LQ_N,
        (long long)LP_N * LQ_N, (long long)LQ_N * H_N, (long long)LP_N * H_N);
}

// Round 2
// 402.938 us; speedup vs baseline: 3.1158x; 3.1158x over previous
//
#include <hip/hip_runtime.h>
#include <hip/hip_bf16.h>

#define B_N 16
#define LP_N 1024
#define LQ_N 1024
#define H_N 1024

typedef unsigned short u16;
typedef __attribute__((ext_vector_type(8))) short bf16x8;
typedef __attribute__((ext_vector_type(4))) float f32x4;

__device__ __forceinline__ u16 f2bf(float x) {
    __hip_bfloat16 h = __float2bfloat16(x);
    return *(u16*)&h;
}
__device__ __forceinline__ float bf2f(u16 u) {
    __hip_bfloat16 h;
    *(u16*)&h = u;
    return __bfloat162float(h);
}

__device__ __forceinline__ void load_lds16(const u16* g, u16* l) {
    __builtin_amdgcn_global_load_lds(
        (const __attribute__((address_space(1))) void*)g,
        (__attribute__((address_space(3))) void*)l, 16, 0, 0);
}

// ---------------------------------------------------------------------------
// Split-bf16 MFMA GEMM, NT form: C[m][n] = sum_k A[m][k]*B[n][k] (+bias)(relu)
// A: M x K row-major (hi[,lo] bf16), B: N x K row-major (hi[,lo] bf16).
// 128x128 tile, BK=32, 4 waves (2x2 of 64x64), 16x16x32 bf16 MFMA.
// LDS XOR swizzle: physical 16B slot = logical_slot ^ (row&3). Staging
// pre-swizzles the GLOBAL source (linear LDS dest for global_load_lds, m104);
// ds_read applies the same XOR. 2-way bank aliasing only (free per m136).
// EPI: 0 = write fp32, 1 = +bias, split-write bf16 hi/lo, 2 = relu fp32.
// ---------------------------------------------------------------------------
template<bool SPLIT, int EPI>
__launch_bounds__(256, 2)
__global__ void mfma_gemm(const u16* __restrict__ Ahi, const u16* __restrict__ Alo,
                          const u16* __restrict__ Bhi, const u16* __restrict__ Blo,
                          const float* __restrict__ bias,
                          float* __restrict__ Cf, u16* __restrict__ Chi, u16* __restrict__ Clo,
                          int N, int K,
                          long long sA, long long sB, long long sC)
{
    constexpr int NTILES = SPLIT ? 4 : 2;
    __shared__ __align__(16) u16 lds[NTILES * 4096];   // 4096 u16 = 8 KB per 128x32 tile
    u16* As_hi = lds;
    u16* Bs_hi = lds + 4096;
    u16* As_lo = SPLIT ? lds + 8192 : lds;
    u16* Bs_lo = SPLIT ? lds + 12288 : lds;

    const int tid  = threadIdx.x;
    const int lane = tid & 63;
    const int wv   = tid >> 6;
    const int wr   = wv >> 1, wc = wv & 1;
    const long long z = blockIdx.z;
    const int bm = blockIdx.y * 128, bn = blockIdx.x * 128;

    Ahi += z * sA; Bhi += z * sB;

    // staging: 512 16B chunks/tile, 2 per thread. chunk c -> row=c>>2, phys
    // slot sp=c&3; global slot = sp ^ (row&3).
    const int c0 = tid, c1 = tid + 256;
    const int r0 = c0 >> 2, s0 = (c0 & 3) ^ (r0 & 3);
    const int r1 = c1 >> 2, s1 = (c1 & 3) ^ (r1 & 3);

    const u16* gA0 = Ahi + (long long)(bm + r0) * K + s0 * 8;
    const u16* gA1 = Ahi + (long long)(bm + r1) * K + s1 * 8;
    const u16* gB0 = Bhi + (long long)(bn + r0) * K + s0 * 8;
    const u16* gB1 = Bhi + (long long)(bn + r1) * K + s1 * 8;
    const u16 *gAl0 = nullptr, *gAl1 = nullptr, *gBl0 = nullptr, *gBl1 = nullptr;
    if constexpr (SPLIT) {
        const u16* Al = Alo + z * sA;
        const u16* Bl = Blo + z * sB;
        gAl0 = Al + (long long)(bm + r0) * K + s0 * 8;
        gAl1 = Al + (long long)(bm + r1) * K + s1 * 8;
        gBl0 = Bl + (long long)(bn + r0) * K + s0 * 8;
        gBl1 = Bl + (long long)(bn + r1) * K + s1 * 8;
    }
    u16* dA0 = As_hi + c0 * 8;  u16* dA1 = As_hi + c1 * 8;
    u16* dB0 = Bs_hi + c0 * 8;  u16* dB1 = Bs_hi + c1 * 8;
    u16* dAl0 = As_lo + c0 * 8; u16* dAl1 = As_lo + c1 * 8;
    u16* dBl0 = Bs_lo + c0 * 8; u16* dBl1 = Bs_lo + c1 * 8;

    // fragment read byte-offsets (within a tile), swizzled
    int offA[4], offB[4];
#pragma unroll
    for (int t = 0; t < 4; ++t) {
        const int ra = wr * 64 + t * 16 + (lane & 15);
        offA[t] = ra * 64 + ((((lane >> 4) ^ ra) & 3) << 4);
        const int rb = wc * 64 + t * 16 + (lane & 15);
        offB[t] = rb * 64 + ((((lane >> 4) ^ rb) & 3) << 4);
    }

    f32x4 acc[4][4];
#pragma unroll
    for (int i = 0; i < 4; ++i)
#pragma unroll
        for (int j = 0; j < 4; ++j)
            acc[i][j] = (f32x4){0.f, 0.f, 0.f, 0.f};

    for (int kt = 0; kt < K; kt += 32) {
        load_lds16(gA0, dA0); load_lds16(gA1, dA1);
        load_lds16(gB0, dB0); load_lds16(gB1, dB1);
        if constexpr (SPLIT) {
            load_lds16(gAl0, dAl0); load_lds16(gAl1, dAl1);
            load_lds16(gBl0, dBl0); load_lds16(gBl1, dBl1);
            gAl0 += 32; gAl1 += 32; gBl0 += 32; gBl1 += 32;
        }
        gA0 += 32; gA1 += 32; gB0 += 32; gB1 += 32;
        __syncthreads();   // compiler emits vmcnt(0) drain before s_barrier

        bf16x8 ah[4], bh[4], al[4], bl[4];
#pragma unroll
        for (int t = 0; t < 4; ++t) {
            ah[t] = *(const bf16x8*)((const char*)As_hi + offA[t]);
            bh[t] = *(const bf16x8*)((const char*)Bs_hi + offB[t]);
            if constexpr (SPLIT) {
                al[t] = *(const bf16x8*)((const char*)As_lo + offA[t]);
                bl[t] = *(const bf16x8*)((const char*)Bs_lo + offB[t]);
            }
        }
#pragma unroll
        for (int i = 0; i < 4; ++i)
#pragma unroll
            for (int j = 0; j < 4; ++j) {
                acc[i][j] = __builtin_amdgcn_mfma_f32_16x16x32_bf16(ah[i], bh[j], acc[i][j], 0, 0, 0);
                if constexpr (SPLIT) {
                    acc[i][j] = __builtin_amdgcn_mfma_f32_16x16x32_bf16(ah[i], bl[j], acc[i][j], 0, 0, 0);
                    acc[i][j] = __builtin_amdgcn_mfma_f32_16x16x32_bf16(al[i], bh[j], acc[i][j], 0, 0, 0);
                }
            }
        __syncthreads();
    }

    // epilogue; C/D map: col = lane&15, row = (lane>>4)*4 + reg  [m89/m91]
    const long long Cbase = z * sC;
#pragma unroll
    for (int i = 0; i < 4; ++i) {
        const int row0 = bm + wr * 64 + i * 16 + ((lane >> 4) << 2);
#pragma unroll
        for (int j = 0; j < 4; ++j) {
            const int col = bn + wc * 64 + j * 16 + (lane & 15);
#pragma unroll
            for (int e = 0; e < 4; ++e) {
                const float v = acc[i][j][e];
                const long long idx = Cbase + (long long)(row0 + e) * N + col;
                if constexpr (EPI == 0) {
                    Cf[idx] = v;
                } else if constexpr (EPI == 1) {
                    const float vb = v + bias[col];
                    const u16 h = f2bf(vb);
                    Chi[idx] = h;
                    Clo[idx] = f2bf(vb - bf2f(h));
                } else {
                    Cf[idx] = fmaxf(v, 0.f);
                }
            }
        }
    }
}

// fp32 -> bf16 hi/lo split, 4 elems/thread
__global__ void split_cvt(const float* __restrict__ in, u16* __restrict__ hi,
                          u16* __restrict__ lo, long long n4)
{
    const long long i = (long long)blockIdx.x * 256 + threadIdx.x;
    if (i >= n4) return;
    const float4 v = ((const float4*)in)[i];
    ushort4 h, l;
    h.x = f2bf(v.x); l.x = f2bf(v.x - bf2f(h.x));
    h.y = f2bf(v.y); l.y = f2bf(v.y - bf2f(h.y));
    h.z = f2bf(v.z); l.z = f2bf(v.z - bf2f(h.z));
    h.w = f2bf(v.w); l.w = f2bf(v.w - bf2f(h.w));
    ((ushort4*)hi)[i] = h;
    ((ushort4*)lo)[i] = l;
}

// out[c][r] = in[r][c] with bf16 (hi[,lo]) conversion; in: R x C per batch z
template<bool LO>
__global__ void transpose_cvt(const float* __restrict__ in, u16* __restrict__ hi,
                              u16* __restrict__ lo, int R, int C,
                              long long sIn, long long sOut)
{
    __shared__ float t[32][33];
    const long long z = blockIdx.z;
    const float* I = in + z * sIn;
    const int r0 = blockIdx.y * 32, c0 = blockIdx.x * 32;
    for (int j = threadIdx.y; j < 32; j += 8)
        t[j][threadIdx.x] = I[(long long)(r0 + j) * C + c0 + threadIdx.x];
    __syncthreads();
    for (int j = threadIdx.y; j < 32; j += 8) {
        const float v = t[threadIdx.x][j];
        const long long o = z * sOut + (long long)(c0 + j) * R + r0 + threadIdx.x;
        const u16 h = f2bf(v);
        hi[o] = h;
        if (LO) lo[o] = f2bf(v - bf2f(h));
    }
}

// row softmax (fp32 in, bf16 out), one 256-thread block per 1024-elem row
__global__ void softmax_bf16(const float* __restrict__ S, u16* __restrict__ A)
{
    const long long row = blockIdx.x;
    const float* r = S + row * (long long)LQ_N;
    const int t = threadIdx.x;
    float4 v = ((const float4*)r)[t];

    float m = fmaxf(fmaxf(v.x, v.y), fmaxf(v.z, v.w));
#pragma unroll
    for (int off = 32; off > 0; off >>= 1)
        m = fmaxf(m, __shfl_xor(m, off));

    __shared__ float red[4];
    const int lane = t & 63, wid = t >> 6;
    if (lane == 0) red[wid] = m;
    __syncthreads();
    m = fmaxf(fmaxf(red[0], red[1]), fmaxf(red[2], red[3]));
    __syncthreads();

    v.x = __expf(v.x - m); v.y = __expf(v.y - m);
    v.z = __expf(v.z - m); v.w = __expf(v.w - m);
    float s = v.x + v.y + v.z + v.w;
#pragma unroll
    for (int off = 32; off > 0; off >>= 1)
        s += __shfl_xor(s, off);
    if (lane == 0) red[wid] = s;
    __syncthreads();
    s = red[0] + red[1] + red[2] + red[3];

    const float inv = 1.0f / s;
    ushort4 o;
    o.x = f2bf(v.x * inv); o.y = f2bf(v.y * inv);
    o.z = f2bf(v.z * inv); o.w = f2bf(v.w * inv);
    ((ushort4*)(A + row * (long long)LQ_N))[t] = o;
}

// ---------------------------------------------------------------------------
// Fallback fp32 path (round-1 kernel, needs only 128 MB ws)
// ---------------------------------------------------------------------------
#define BM 128
#define BN 128
#define BK 8
#define TM 8
#define TN 8

template<bool TRANSB, bool BIAS, bool RELU>
__launch_bounds__(256)
__global__ void gemm_k(const float* __restrict__ A, const float* __restrict__ Bmat,
                       const float* __restrict__ bias, float* __restrict__ C,
                       int M, int N, int K,
                       long long sA, long long sB, long long sC)
{
    __shared__ float As[BK][BM];
    __shared__ float Bs[BK][BN];
    const int tid = threadIdx.x;
    const int tx = tid & 15;
    const int ty = tid >> 4;
    const int bn = blockIdx.x * BN;
    const int bm = blockIdx.y * BM;
    const long long z = blockIdx.z;
    A += z * sA; Bmat += z * sB; C += z * sC;
    float acc[TM][TN];
#pragma unroll
    for (int i = 0; i < TM; i++)
#pragma unroll
        for (int j = 0; j < TN; j++) acc[i][j] = 0.f;
    const int arow = tid >> 1;
    const int acol = (tid & 1) * 4;
    const int bk_n = tid >> 5;
    const int bn_n = (tid & 31) * 4;
    for (int k0 = 0; k0 < K; k0 += BK) {
        float4 a4 = *(const float4*)&A[(long long)(bm + arow) * K + k0 + acol];
        As[acol + 0][arow] = a4.x; As[acol + 1][arow] = a4.y;
        As[acol + 2][arow] = a4.z; As[acol + 3][arow] = a4.w;
        if (TRANSB) {
            float4 b4 = *(const float4*)&Bmat[(long long)(bn + arow) * K + k0 + acol];
            Bs[acol + 0][arow] = b4.x; Bs[acol + 1][arow] = b4.y;
            Bs[acol + 2][arow] = b4.z; Bs[acol + 3][arow] = b4.w;
        } else {
            float4 b4 = *(const float4*)&Bmat[(long long)(k0 + bk_n) * N + bn + bn_n];
            *(float4*)&Bs[bk_n][bn_n] = b4;
        }
        __syncthreads();
#pragma unroll
        for (int k = 0; k < BK; k++) {
            float a[TM], b[TN];
            *(float4*)&a[0] = *(const float4*)&As[k][ty * TM];
            *(float4*)&a[4] = *(const float4*)&As[k][ty * TM + 4];
            *(float4*)&b[0] = *(const float4*)&Bs[k][tx * TN];
            *(float4*)&b[4] = *(const float4*)&Bs[k][tx * TN + 4];
#pragma unroll
            for (int i = 0; i < TM; i++)
#pragma unroll
                for (int j = 0; j < TN; j++)
                    acc[i][j] = fmaf(a[i], b[j], acc[i][j]);
        }
        __syncthreads();
    }
#pragma unroll
    for (int i = 0; i < TM; i++) {
        const int row = bm + ty * TM + i;
#pragma unroll
        for (int j = 0; j < TN; j += 4) {
            const int col = bn + tx * TN + j;
            float4 v;
            v.x = acc[i][j + 0]; v.y = acc[i][j + 1];
            v.z = acc[i][j + 2]; v.w = acc[i][j + 3];
            if (BIAS) {
                v.x += bias[col + 0]; v.y += bias[col + 1];
                v.z += bias[col + 2]; v.w += bias[col + 3];
            }
            if (RELU) {
                v.x = fmaxf(v.x, 0.f); v.y = fmaxf(v.y, 0.f);
                v.z = fmaxf(v.z, 0.f); v.w = fmaxf(v.w, 0.f);
            }
            *(float4*)&C[(long long)row * N + col] = v;
        }
    }
}

__global__ void softmax_k(float* __restrict__ S)
{
    const long long row = blockIdx.x;
    float* r = S + row * (long long)LQ_N;
    const int t = threadIdx.x;
    float4 v = ((float4*)r)[t];
    float m = fmaxf(fmaxf(v.x, v.y), fmaxf(v.z, v.w));
#pragma unroll
    for (int off = 32; off > 0; off >>= 1)
        m = fmaxf(m, __shfl_xor(m, off));
    __shared__ float red[4];
    const int lane = t & 63, wid = t >> 6;
    if (lane == 0) red[wid] = m;
    __syncthreads();
    m = fmaxf(fmaxf(red[0], red[1]), fmaxf(red[2], red[3]));
    __syncthreads();
    v.x = __expf(v.x - m); v.y = __expf(v.y - m);
    v.z = __expf(v.z - m); v.w = __expf(v.w - m);
    float s = v.x + v.y + v.z + v.w;
#pragma unroll
    for (int off = 32; off > 0; off >>= 1)
        s += __shfl_xor(s, off);
    if (lane == 0) red[wid] = s;
    __syncthreads();
    s = red[0] + red[1] + red[2] + red[3];
    const float inv = 1.0f / s;
    v.x *= inv; v.y *= inv; v.z *= inv; v.w *= inv;
    ((float4*)r)[t] = v;
}

extern "C" void kernel_launch(void* const* d_in, const int* in_sizes, int n_in,
                              void* d_out, int out_size, void* d_ws, size_t ws_size,
                              hipStream_t stream)
{
    const float* p    = (const float*)d_in[0];
    const float* q    = (const float*)d_in[1];
    const float* W    = (const float*)d_in[2];
    const float* bias = (const float*)d_in[3];
    float* out = (float*)d_out;

    const size_t MB32 = 33554432ull;          // 16M bf16
    const size_t NEED = 7 * MB32 + 2 * 2097152ull;  // 228 MB + 4 MB

    if (ws_size >= NEED) {
        char* w = (char*)d_ws;
        u16* p_hi    = (u16*)(w + 0 * MB32);
        u16* p_lo    = (u16*)(w + 1 * MB32);
        u16* q_hi    = (u16*)(w + 2 * MB32);
        u16* q_lo    = (u16*)(w + 3 * MB32);
        u16* keys_hi = (u16*)(w + 4 * MB32);
        u16* keys_lo = (u16*)(w + 5 * MB32);
        u16* qT_hi   = (u16*)(w + 6 * MB32);
        u16* Wt_hi   = (u16*)(w + 7 * MB32);
        u16* Wt_lo   = (u16*)(w + 7 * MB32 + 2097152);
        float* scores = (float*)(w + 2 * MB32);  // reuses q_hi/q_lo after GEMM1
        u16* attn     = (u16*)(w + 0 * MB32);    // reuses p_hi after GEMM2

        const long long n4 = (long long)B_N * LQ_N * H_N / 4;  // 4 Mi float4s
        split_cvt<<<dim3((unsigned)(n4 / 256)), 256, 0, stream>>>(p, p_hi, p_lo, n4);
        split_cvt<<<dim3((unsigned)(n4 / 256)), 256, 0, stream>>>(q, q_hi, q_lo, n4);
        transpose_cvt<true><<<dim3(32, 32, 1), dim3(32, 8), 0, stream>>>(
            W, Wt_hi, Wt_lo, H_N, H_N, 0, 0);
        transpose_cvt<false><<<dim3(32, 32, B_N), dim3(32, 8), 0, stream>>>(
            q, qT_hi, nullptr, LQ_N, H_N,
            (long long)LQ_N * H_N, (long long)LQ_N * H_N);

        // keys = q @ W + b  (M = B*LQ folds batch; split, bias, bf16-split out)
        mfma_gemm<true, 1><<<dim3(8, 128, 1), 256, 0, stream>>>(
            q_hi, q_lo, Wt_hi, Wt_lo, bias, nullptr, keys_hi, keys_lo,
            H_N, H_N, 0, 0, 0);

        // scores[b] = p[b] @ keys[b]^T  (split, fp32 out)
        mfma_gemm<true, 0><<<dim3(8, 8, B_N), 256, 0, stream>>>(
            p_hi, p_lo, keys_hi, keys_lo, nullptr, scores, nullptr, nullptr,
            LQ_N, H_N,
            (long long)LP_N * H_N, (long long)LQ_N * H_N, (long long)LP_N * LQ_N);

        softmax_bf16<<<B_N * LP_N, 256, 0, stream>>>(scores, attn);

        // out[b] = relu(attn[b] @ q[b])  (direct bf16, relu fp32 out)
        mfma_gemm<false, 2><<<dim3(8, 8, B_N), 256, 0, stream>>>(
            attn, nullptr, qT_hi, nullptr, nullptr, out, nullptr, nullptr,
            H_N, LQ_N,
            (long long)LP_N * LQ_N, (long long)H_N * LQ_N, (long long)LP_N * H_N);
    } else {
        // fp32 fallback (verified round 1)
        float* keys   = (float*)d_ws;
        float* scores = keys + (long long)B_N * LQ_N * H_N;

        gemm_k<false, true, false><<<dim3(H_N / BN, (B_N * LQ_N) / BM, 1), 256, 0, stream>>>(
            q, W, bias, keys, B_N * LQ_N, H_N, H_N, 0, 0, 0);
        gemm_k<true, false, false><<<dim3(LQ_N / BN, LP_N / BM, B_N), 256, 0, stream>>>(
            p, keys, nullptr, scores, LP_N, LQ_N, H_N,
            (long long)LP_N * H_N, (long long)LQ_N * H_N, (long long)LP_N * LQ_N);
        softmax_k<<<B_N * LP_N, 256, 0, stream>>>(scores);
        gemm_k<false, false, true><<<dim3(H_N / BN, LP_N / BM, B_N), 256, 0, stream>>>(
            scores, q, nullptr, out, LP_N, H_N, LQ_N,
            (long long)LP_N * LQ_N, (long long)LQ_N * H_N, (long long)LP_N * H_N);
    }
}

// Round 3
// 306.520 us; speedup vs baseline: 4.0959x; 1.3146x over previous
//
#include <hip/hip_runtime.h>
#include <hip/hip_bf16.h>

#define B_N 16
#define LP_N 1024
#define LQ_N 1024
#define H_N 1024

typedef unsigned short u16;
typedef __attribute__((ext_vector_type(8))) short bf16x8;
typedef __attribute__((ext_vector_type(4))) float f32x4;

__device__ __forceinline__ u16 f2bf(float x) {
    __hip_bfloat16 h = __float2bfloat16(x);
    return *(u16*)&h;
}
__device__ __forceinline__ float bf2f(u16 u) {
    __hip_bfloat16 h;
    *(u16*)&h = u;
    return __bfloat162float(h);
}

__device__ __forceinline__ void load_lds16(const u16* g, u16* l) {
    __builtin_amdgcn_global_load_lds(
        (const __attribute__((address_space(1))) void*)g,
        (__attribute__((address_space(3))) void*)l, 16, 0, 0);
}

// ---------------------------------------------------------------------------
// 256x256-tile split-bf16 MFMA GEMM, NT form: C[m][n] = sum_k A[m][k]*B[n][k]
// BK=32, 8 waves (2M x 4N), per-wave output 128x64 (8x4 frags of 16x16).
// Swizzle: 16B slot s_phys = s_log ^ ((row>>1)&3)  — balanced: a 16-row x 64B
//   ds_read_b128 frag hits every bank exactly 8x (b128 floor), vs 2x imbalance
//   of the old (row&3) XOR (8.4M conflicts/dispatch measured in R2).
//   Applied identically on the pre-swizzled GLOBAL source (linear LDS dest,
//   required by global_load_lds) and on the ds_read side (rule #21).
// Pipeline: depth-1 prefetch. buf0/buf1 are DISTINCT __shared__ objects and
//   the K-loop is unrolled x2 so the compiler can prove the t+1 stage
//   (gload_lds -> other buffer) doesn't alias the ds_reads of the current
//   buffer — no forced vmcnt(0) before compute. One __syncthreads() per
//   K-step provides the vmcnt(0)+barrier for the staged tile.
// EPI: 0 = fp32 store, 1 = +bias & split bf16 hi/lo store, 2 = relu fp32.
// ---------------------------------------------------------------------------
template<bool SPLIT, int EPI>
__launch_bounds__(512, 2)
__global__ void gemm8(const u16* __restrict__ Ahi, const u16* __restrict__ Alo,
                      const u16* __restrict__ Bhi, const u16* __restrict__ Blo,
                      const float* __restrict__ bias,
                      float* __restrict__ Cf, u16* __restrict__ Chi, u16* __restrict__ Clo,
                      int N, int K, int gn, int gmn,
                      long long sA, long long sB, long long sC)
{
    constexpr int SUB = 8192;                 // u16 per 256x32 sub-tile (16 KB)
    constexpr int NSUB = SPLIT ? 4 : 2;       // [A_hi, A_lo, B_hi, B_lo] | [A_hi, B_hi]
    constexpr int BH  = SPLIT ? 2 * SUB : SUB;
    __shared__ __align__(16) u16 buf0[NSUB * SUB];
    __shared__ __align__(16) u16 buf1[NSUB * SUB];

    const int tid  = threadIdx.x;
    const int lane = tid & 63;
    const int wv   = tid >> 6;
    const int wr   = wv >> 2, wc = wv & 3;    // 2M x 4N waves

    // XCD-contiguous block swizzle (nwg=256, 32 blocks/XCD)
    const int d   = blockIdx.x;
    const int cpx = gridDim.x >> 3;
    const int swz = (d & 7) * cpx + (d >> 3);
    const long long z = swz / gmn;
    const int r_  = swz % gmn;
    const int bm  = (r_ / gn) * 256;
    const int bn  = (r_ % gn) * 256;

    // staging: each sub-tile = 1024 16B chunks; thread handles c0, c1.
    const int c0 = tid, c1 = tid + 512;
    const int r0 = c0 >> 2, s0 = (c0 & 3) ^ ((r0 >> 1) & 3);
    const int r1 = c1 >> 2, s1 = (c1 & 3) ^ ((r1 >> 1) & 3);

    const u16* pAh0 = Ahi + z * sA + (long long)(bm + r0) * K + s0 * 8;
    const u16* pAh1 = Ahi + z * sA + (long long)(bm + r1) * K + s1 * 8;
    const u16* pBh0 = Bhi + z * sB + (long long)(bn + r0) * K + s0 * 8;
    const u16* pBh1 = Bhi + z * sB + (long long)(bn + r1) * K + s1 * 8;
    const u16 *pAl0 = nullptr, *pAl1 = nullptr, *pBl0 = nullptr, *pBl1 = nullptr;
    if constexpr (SPLIT) {
        pAl0 = Alo + z * sA + (long long)(bm + r0) * K + s0 * 8;
        pAl1 = Alo + z * sA + (long long)(bm + r1) * K + s1 * 8;
        pBl0 = Blo + z * sB + (long long)(bn + r0) * K + s0 * 8;
        pBl1 = Blo + z * sB + (long long)(bn + r1) * K + s1 * 8;
    }

    // fragment read offsets (u16 units, within a sub-tile), same swizzle
    int offA[8], offB[4];
#pragma unroll
    for (int i = 0; i < 8; ++i) {
        const int ra = wr * 128 + i * 16 + (lane & 15);
        offA[i] = ra * 32 + (((lane >> 4) ^ ((ra >> 1) & 3)) << 3);
    }
#pragma unroll
    for (int j = 0; j < 4; ++j) {
        const int rb = wc * 64 + j * 16 + (lane & 15);
        offB[j] = rb * 32 + (((lane >> 4) ^ ((rb >> 1) & 3)) << 3);
    }

    f32x4 acc[8][4];
#pragma unroll
    for (int i = 0; i < 8; ++i)
#pragma unroll
        for (int j = 0; j < 4; ++j)
            acc[i][j] = (f32x4){0.f, 0.f, 0.f, 0.f};

#define STAGE(BASE) do {                                                      \
        load_lds16(pAh0, (BASE) + c0 * 8);      load_lds16(pAh1, (BASE) + c1 * 8); \
        load_lds16(pBh0, (BASE) + BH + c0 * 8); load_lds16(pBh1, (BASE) + BH + c1 * 8); \
        if constexpr (SPLIT) {                                                \
            load_lds16(pAl0, (BASE) + SUB + c0 * 8);                          \
            load_lds16(pAl1, (BASE) + SUB + c1 * 8);                          \
            load_lds16(pBl0, (BASE) + 3 * SUB + c0 * 8);                      \
            load_lds16(pBl1, (BASE) + 3 * SUB + c1 * 8);                      \
            pAl0 += 32; pAl1 += 32; pBl0 += 32; pBl1 += 32;                   \
        }                                                                     \
        pAh0 += 32; pAh1 += 32; pBh0 += 32; pBh1 += 32;                       \
    } while (0)

#define COMPUTE(BASE) do {                                                    \
        bf16x8 bh[4], bl[4];                                                  \
        _Pragma("unroll")                                                     \
        for (int j = 0; j < 4; ++j) {                                         \
            bh[j] = *(const bf16x8*)((BASE) + BH + offB[j]);                  \
            if constexpr (SPLIT)                                              \
                bl[j] = *(const bf16x8*)((BASE) + 3 * SUB + offB[j]);         \
        }                                                                     \
        __builtin_amdgcn_s_setprio(1);                                        \
        _Pragma("unroll")                                                     \
        for (int i = 0; i < 8; ++i) {                                         \
            const bf16x8 ah = *(const bf16x8*)((BASE) + offA[i]);             \
            _Pragma("unroll")                                                 \
            for (int j = 0; j < 4; ++j)                                       \
                acc[i][j] = __builtin_amdgcn_mfma_f32_16x16x32_bf16(ah, bh[j], acc[i][j], 0, 0, 0); \
            if constexpr (SPLIT) {                                            \
                const bf16x8 al = *(const bf16x8*)((BASE) + SUB + offA[i]);   \
                _Pragma("unroll")                                             \
                for (int j = 0; j < 4; ++j)                                   \
                    acc[i][j] = __builtin_amdgcn_mfma_f32_16x16x32_bf16(ah, bl[j], acc[i][j], 0, 0, 0); \
                _Pragma("unroll")                                             \
                for (int j = 0; j < 4; ++j)                                   \
                    acc[i][j] = __builtin_amdgcn_mfma_f32_16x16x32_bf16(al, bh[j], acc[i][j], 0, 0, 0); \
            }                                                                 \
        }                                                                     \
        __builtin_amdgcn_s_setprio(0);                                        \
    } while (0)

    const int NTs = K >> 5;       // 32 K-steps

    STAGE(buf0);                  // tile 0
    __syncthreads();

    for (int t = 0; t < NTs; t += 2) {
        if (t + 1 < NTs) STAGE(buf1);   // prefetch tile t+1 while computing t
        COMPUTE(buf0);
        __syncthreads();                 // drains vmcnt(0): tile t+1 landed
        if (t + 2 < NTs) STAGE(buf0);
        COMPUTE(buf1);
        __syncthreads();
    }
#undef STAGE
#undef COMPUTE

    // epilogue; C/D map: col = lane&15, row = (lane>>4)*4 + e  [m89/m91]
    const long long Cbase = z * sC;
#pragma unroll
    for (int i = 0; i < 8; ++i) {
        const int row0 = bm + wr * 128 + i * 16 + ((lane >> 4) << 2);
#pragma unroll
        for (int j = 0; j < 4; ++j) {
            const int col = bn + wc * 64 + j * 16 + (lane & 15);
#pragma unroll
            for (int e = 0; e < 4; ++e) {
                const float v = acc[i][j][e];
                const long long idx = Cbase + (long long)(row0 + e) * N + col;
                if constexpr (EPI == 0) {
                    Cf[idx] = v;
                } else if constexpr (EPI == 1) {
                    const float vb = v + bias[col];
                    const u16 h = f2bf(vb);
                    Chi[idx] = h;
                    Clo[idx] = f2bf(vb - bf2f(h));
                } else {
                    Cf[idx] = fmaxf(v, 0.f);
                }
            }
        }
    }
}

// fp32 -> bf16 hi/lo split, 4 elems/thread
__global__ void split_cvt(const float* __restrict__ in, u16* __restrict__ hi,
                          u16* __restrict__ lo, long long n4)
{
    const long long i = (long long)blockIdx.x * 256 + threadIdx.x;
    if (i >= n4) return;
    const float4 v = ((const float4*)in)[i];
    ushort4 h, l;
    h.x = f2bf(v.x); l.x = f2bf(v.x - bf2f(h.x));
    h.y = f2bf(v.y); l.y = f2bf(v.y - bf2f(h.y));
    h.z = f2bf(v.z); l.z = f2bf(v.z - bf2f(h.z));
    h.w = f2bf(v.w); l.w = f2bf(v.w - bf2f(h.w));
    ((ushort4*)hi)[i] = h;
    ((ushort4*)lo)[i] = l;
}

// out[c][r] = in[r][c] with bf16 (hi[,lo]) conversion; in: R x C per batch z
template<bool LO>
__global__ void transpose_cvt(const float* __restrict__ in, u16* __restrict__ hi,
                              u16* __restrict__ lo, int R, int C,
                              long long sIn, long long sOut)
{
    __shared__ float t[32][33];
    const long long z = blockIdx.z;
    const float* I = in + z * sIn;
    const int r0 = blockIdx.y * 32, c0 = blockIdx.x * 32;
    for (int j = threadIdx.y; j < 32; j += 8)
        t[j][threadIdx.x] = I[(long long)(r0 + j) * C + c0 + threadIdx.x];
    __syncthreads();
    for (int j = threadIdx.y; j < 32; j += 8) {
        const float v = t[threadIdx.x][j];
        const long long o = z * sOut + (long long)(c0 + j) * R + r0 + threadIdx.x;
        const u16 h = f2bf(v);
        hi[o] = h;
        if (LO) lo[o] = f2bf(v - bf2f(h));
    }
}

// row softmax (fp32 in, bf16 out), one 256-thread block per 1024-elem row
__global__ void softmax_bf16(const float* __restrict__ S, u16* __restrict__ A)
{
    const long long row = blockIdx.x;
    const float* r = S + row * (long long)LQ_N;
    const int t = threadIdx.x;
    float4 v = ((const float4*)r)[t];

    float m = fmaxf(fmaxf(v.x, v.y), fmaxf(v.z, v.w));
#pragma unroll
    for (int off = 32; off > 0; off >>= 1)
        m = fmaxf(m, __shfl_xor(m, off));

    __shared__ float red[4];
    const int lane = t & 63, wid = t >> 6;
    if (lane == 0) red[wid] = m;
    __syncthreads();
    m = fmaxf(fmaxf(red[0], red[1]), fmaxf(red[2], red[3]));
    __syncthreads();

    v.x = __expf(v.x - m); v.y = __expf(v.y - m);
    v.z = __expf(v.z - m); v.w = __expf(v.w - m);
    float s = v.x + v.y + v.z + v.w;
#pragma unroll
    for (int off = 32; off > 0; off >>= 1)
        s += __shfl_xor(s, off);
    if (lane == 0) red[wid] = s;
    __syncthreads();
    s = red[0] + red[1] + red[2] + red[3];

    const float inv = 1.0f / s;
    ushort4 o;
    o.x = f2bf(v.x * inv); o.y = f2bf(v.y * inv);
    o.z = f2bf(v.z * inv); o.w = f2bf(v.w * inv);
    ((ushort4*)(A + row * (long long)LQ_N))[t] = o;
}

// ---------------------------------------------------------------------------
// Fallback fp32 path (round-1, verified; needs only 128 MB ws)
// ---------------------------------------------------------------------------
#define BM 128
#define BN 128
#define BK 8
#define TM 8
#define TN 8

template<bool TRANSB, bool BIAS, bool RELU>
__launch_bounds__(256)
__global__ void gemm_k(const float* __restrict__ A, const float* __restrict__ Bmat,
                       const float* __restrict__ bias, float* __restrict__ C,
                       int M, int N, int K,
                       long long sA, long long sB, long long sC)
{
    __shared__ float As[BK][BM];
    __shared__ float Bs[BK][BN];
    const int tid = threadIdx.x;
    const int tx = tid & 15;
    const int ty = tid >> 4;
    const int bn = blockIdx.x * BN;
    const int bm = blockIdx.y * BM;
    const long long z = blockIdx.z;
    A += z * sA; Bmat += z * sB; C += z * sC;
    float acc[TM][TN];
#pragma unroll
    for (int i = 0; i < TM; i++)
#pragma unroll
        for (int j = 0; j < TN; j++) acc[i][j] = 0.f;
    const int arow = tid >> 1;
    const int acol = (tid & 1) * 4;
    const int bk_n = tid >> 5;
    const int bn_n = (tid & 31) * 4;
    for (int k0 = 0; k0 < K; k0 += BK) {
        float4 a4 = *(const float4*)&A[(long long)(bm + arow) * K + k0 + acol];
        As[acol + 0][arow] = a4.x; As[acol + 1][arow] = a4.y;
        As[acol + 2][arow] = a4.z; As[acol + 3][arow] = a4.w;
        if (TRANSB) {
            float4 b4 = *(const float4*)&Bmat[(long long)(bn + arow) * K + k0 + acol];
            Bs[acol + 0][arow] = b4.x; Bs[acol + 1][arow] = b4.y;
            Bs[acol + 2][arow] = b4.z; Bs[acol + 3][arow] = b4.w;
        } else {
            float4 b4 = *(const float4*)&Bmat[(long long)(k0 + bk_n) * N + bn + bn_n];
            *(float4*)&Bs[bk_n][bn_n] = b4;
        }
        __syncthreads();
#pragma unroll
        for (int k = 0; k < BK; k++) {
            float a[TM], b[TN];
            *(float4*)&a[0] = *(const float4*)&As[k][ty * TM];
            *(float4*)&a[4] = *(const float4*)&As[k][ty * TM + 4];
            *(float4*)&b[0] = *(const float4*)&Bs[k][tx * TN];
            *(float4*)&b[4] = *(const float4*)&Bs[k][tx * TN + 4];
#pragma unroll
            for (int i = 0; i < TM; i++)
#pragma unroll
                for (int j = 0; j < TN; j++)
                    acc[i][j] = fmaf(a[i], b[j], acc[i][j]);
        }
        __syncthreads();
    }
#pragma unroll
    for (int i = 0; i < TM; i++) {
        const int row = bm + ty * TM + i;
#pragma unroll
        for (int j = 0; j < TN; j += 4) {
            const int col = bn + tx * TN + j;
            float4 v;
            v.x = acc[i][j + 0]; v.y = acc[i][j + 1];
            v.z = acc[i][j + 2]; v.w = acc[i][j + 3];
            if (BIAS) {
                v.x += bias[col + 0]; v.y += bias[col + 1];
                v.z += bias[col + 2]; v.w += bias[col + 3];
            }
            if (RELU) {
                v.x = fmaxf(v.x, 0.f); v.y = fmaxf(v.y, 0.f);
                v.z = fmaxf(v.z, 0.f); v.w = fmaxf(v.w, 0.f);
            }
            *(float4*)&C[(long long)row * N + col] = v;
        }
    }
}

__global__ void softmax_k(float* __restrict__ S)
{
    const long long row = blockIdx.x;
    float* r = S + row * (long long)LQ_N;
    const int t = threadIdx.x;
    float4 v = ((float4*)r)[t];
    float m = fmaxf(fmaxf(v.x, v.y), fmaxf(v.z, v.w));
#pragma unroll
    for (int off = 32; off > 0; off >>= 1)
        m = fmaxf(m, __shfl_xor(m, off));
    __shared__ float red[4];
    const int lane = t & 63, wid = t >> 6;
    if (lane == 0) red[wid] = m;
    __syncthreads();
    m = fmaxf(fmaxf(red[0], red[1]), fmaxf(red[2], red[3]));
    __syncthreads();
    v.x = __expf(v.x - m); v.y = __expf(v.y - m);
    v.z = __expf(v.z - m); v.w = __expf(v.w - m);
    float s = v.x + v.y + v.z + v.w;
#pragma unroll
    for (int off = 32; off > 0; off >>= 1)
        s += __shfl_xor(s, off);
    if (lane == 0) red[wid] = s;
    __syncthreads();
    s = red[0] + red[1] + red[2] + red[3];
    const float inv = 1.0f / s;
    v.x *= inv; v.y *= inv; v.z *= inv; v.w *= inv;
    ((float4*)r)[t] = v;
}

extern "C" void kernel_launch(void* const* d_in, const int* in_sizes, int n_in,
                              void* d_out, int out_size, void* d_ws, size_t ws_size,
                              hipStream_t stream)
{
    const float* p    = (const float*)d_in[0];
    const float* q    = (const float*)d_in[1];
    const float* W    = (const float*)d_in[2];
    const float* bias = (const float*)d_in[3];
    float* out = (float*)d_out;

    const size_t MB32 = 33554432ull;                 // 16M bf16
    const size_t NEED = 7 * MB32 + 2 * 2097152ull;   // 228 MB + 4 MB

    if (ws_size >= NEED) {
        char* w = (char*)d_ws;
        u16* p_hi    = (u16*)(w + 0 * MB32);
        u16* p_lo    = (u16*)(w + 1 * MB32);
        u16* q_hi    = (u16*)(w + 2 * MB32);
        u16* q_lo    = (u16*)(w + 3 * MB32);
        u16* keys_hi = (u16*)(w + 4 * MB32);
        u16* keys_lo = (u16*)(w + 5 * MB32);
        u16* qT_hi   = (u16*)(w + 6 * MB32);
        u16* Wt_hi   = (u16*)(w + 7 * MB32);
        u16* Wt_lo   = (u16*)(w + 7 * MB32 + 2097152);
        float* scores = (float*)(w + 2 * MB32);  // reuses q_hi/q_lo after GEMM1
        u16* attn     = (u16*)(w + 0 * MB32);    // reuses p_hi after GEMM2

        const long long n4 = (long long)B_N * LQ_N * H_N / 4;
        split_cvt<<<dim3((unsigned)(n4 / 256)), 256, 0, stream>>>(p, p_hi, p_lo, n4);
        split_cvt<<<dim3((unsigned)(n4 / 256)), 256, 0, stream>>>(q, q_hi, q_lo, n4);
        transpose_cvt<true><<<dim3(32, 32, 1), dim3(32, 8), 0, stream>>>(
            W, Wt_hi, Wt_lo, H_N, H_N, 0, 0);
        transpose_cvt<false><<<dim3(32, 32, B_N), dim3(32, 8), 0, stream>>>(
            q, qT_hi, nullptr, LQ_N, H_N,
            (long long)LQ_N * H_N, (long long)LQ_N * H_N);

        // keys = q @ W + b : M=16384 (batch folded), N=1024. grid 64x4 = 256.
        gemm8<true, 1><<<256, 512, 0, stream>>>(
            q_hi, q_lo, Wt_hi, Wt_lo, bias, nullptr, keys_hi, keys_lo,
            H_N, H_N, /*gn=*/4, /*gmn=*/256, 0, 0, 0);

        // scores[b] = p[b] @ keys[b]^T : per batch 4x4 blocks, z=16. grid 256.
        gemm8<true, 0><<<256, 512, 0, stream>>>(
            p_hi, p_lo, keys_hi, keys_lo, nullptr, scores, nullptr, nullptr,
            LQ_N, H_N, /*gn=*/4, /*gmn=*/16,
            (long long)LP_N * H_N, (long long)LQ_N * H_N, (long long)LP_N * LQ_N);

        softmax_bf16<<<B_N * LP_N, 256, 0, stream>>>(scores, attn);

        // out[b] = relu(attn[b] @ q[b]) : dense bf16. grid 256.
        gemm8<false, 2><<<256, 512, 0, stream>>>(
            attn, nullptr, qT_hi, nullptr, nullptr, out, nullptr, nullptr,
            H_N, LQ_N, /*gn=*/4, /*gmn=*/16,
            (long long)LP_N * LQ_N, (long long)H_N * LQ_N, (long long)LP_N * H_N);
    } else {
        float* keys   = (float*)d_ws;
        float* scores = keys + (long long)B_N * LQ_N * H_N;

        gemm_k<false, true, false><<<dim3(H_N / BN, (B_N * LQ_N) / BM, 1), 256, 0, stream>>>(
            q, W, bias, keys, B_N * LQ_N, H_N, H_N, 0, 0, 0);
        gemm_k<true, false, false><<<dim3(LQ_N / BN, LP_N / BM, B_N), 256, 0, stream>>>(
            p, keys, nullptr, scores, LP_N, LQ_N, H_N,
            (long long)LP_N * H_N, (long long)LQ_N * H_N, (long long)LP_N * LQ_N);
        softmax_k<<<B_N * LP_N, 256, 0, stream>>>(scores);
        gemm_k<false, false, true><<<dim3(H_N / BN, LP_N / BM, B_N), 256, 0, stream>>>(
            scores, q, nullptr, out, LP_N, H_N, LQ_N,
            (long long)LP_N * LQ_N, (long long)LQ_N * H_N, (long long)LP_N * H_N);
    }
}